// Round 11
// baseline (88.436 us; speedup 1.0000x reference)
//
#include <hip/hip_runtime.h>

#define NN 10000
#define NE 320000
#define CAP 96

typedef __bf16 bf16x8 __attribute__((ext_vector_type(8)));
typedef float f32x4 __attribute__((ext_vector_type(4)));
typedef unsigned short us8 __attribute__((ext_vector_type(8)));

static __device__ __forceinline__ unsigned short f2bf(float f) {
  union { float fv; unsigned u; } v; v.fv = f;
  unsigned r = v.u + 0x7FFFu + ((v.u >> 16) & 1u);
  return (unsigned short)(r >> 16);
}
static __device__ __forceinline__ float bf2f(unsigned short b) {
  union { unsigned u; float f; } v; v.u = ((unsigned)b) << 16;
  return v.f;
}

// ---- D1: x->bf16 (blocks 0..2499) + cnt zero + weight transpose
//      (blocks 2500..2531). r8-validated verbatim. -------------------------

__global__ __launch_bounds__(256) void conv_k(const float* __restrict__ x,
                                              const float* __restrict__ w1,
                                              const float* __restrict__ w2,
                                              ushort4* __restrict__ xb4,
                                              unsigned short* __restrict__ w1t,
                                              unsigned short* __restrict__ w2t,
                                              int* __restrict__ cnt) {
  __shared__ unsigned short sh[64][72];
  int bid = blockIdx.x, tid = threadIdx.x;
  if (bid < 2500) {
    int t = bid * 256 + tid;
    if (t < 10240) cnt[t] = 0;
    float4 v = reinterpret_cast<const float4*>(x)[t];
    ushort4 o;
    o.x = f2bf(v.x); o.y = f2bf(v.y); o.z = f2bf(v.z); o.w = f2bf(v.w);
    xb4[t] = o;
  } else {
    int b2 = bid - 2500;                       // 0..31
    const float* w = (b2 & 16) ? w2 : w1;
    unsigned short* wt = (b2 & 16) ? w2t : w1t;
    int tile = b2 & 15;
    int ki0 = (tile >> 2) * 64, ni0 = (tile & 3) * 64;
    int r = tid >> 4, c = tid & 15;
#pragma unroll
    for (int rr = r; rr < 64; rr += 16) {
      float4 v = *reinterpret_cast<const float4*>(&w[(ki0 + rr) * 256 + ni0 + c * 4]);
      ushort4 o;
      o.x = f2bf(v.x); o.y = f2bf(v.y); o.z = f2bf(v.z); o.w = f2bf(v.w);
      *reinterpret_cast<ushort4*>(&sh[rr][c * 4]) = o;
    }
    __syncthreads();
    int n = tid >> 3, c8 = tid & 7;
#pragma unroll
    for (int nn = n; nn < 64; nn += 32) {
      us8 o;
#pragma unroll
      for (int j = 0; j < 8; ++j) o[j] = sh[c8 * 8 + j][nn];
      *reinterpret_cast<us8*>(&wt[(ni0 + nn) * 256 + ki0 + c8 * 8]) = o;
    }
  }
}

// ---- D2: bucket fill (4 edges / thread, r8-validated verbatim) ------------

__global__ __launch_bounds__(256) void fill_k(const int* __restrict__ ei,
                                              int* __restrict__ cnt,
                                              int* __restrict__ bucket) {
  int e = (blockIdx.x * 256 + threadIdx.x) * 4;
  if (e < NE) {
    int4 s = *reinterpret_cast<const int4*>(&ei[e]);
    int4 d = *reinterpret_cast<const int4*>(&ei[NE + e]);
    int p;
    p = atomicAdd(&cnt[d.x], 1); if (p < CAP) bucket[d.x * CAP + p] = s.x;
    p = atomicAdd(&cnt[d.y], 1); if (p < CAP) bucket[d.y * CAP + p] = s.y;
    p = atomicAdd(&cnt[d.z], 1); if (p < CAP) bucket[d.z * CAP + p] = s.z;
    p = atomicAdd(&cnt[d.w], 1); if (p < CAP) bucket[d.w * CAP + p] = s.w;
  }
}

// ---- D3: fused agg + MLP. 313 blocks x 1024 thr (16 waves). ---------------
// Agg: wave w owns nodes m0+2w, m0+2w+1; even/odd neighbor split across
// half-waves (8 gathers in flight), shfl_xor(32) combine, bf16 result
// written straight into the LDS A-tile (hb eliminated).
// MLP: 2M x 8N waves, acc[2]; weight chunks staged global->reg EARLY
// (issued before previous chunk's MFMAs) then reg->LDS after the barrier.

__global__ __launch_bounds__(1024, 4) void fused_k(
    const us8* __restrict__ xb8, const int* __restrict__ cnt,
    const int* __restrict__ bucket, const float* __restrict__ epsp,
    const unsigned short* __restrict__ w1t, const float* __restrict__ b1,
    const unsigned short* __restrict__ w2t, const float* __restrict__ b2,
    float* __restrict__ out) {
  __shared__ unsigned short As[32][264];  // 16.9 KB
  __shared__ unsigned short Bs[256][72];  // 36.9 KB
  int m0 = blockIdx.x * 32;
  int tid = threadIdx.x, lane = tid & 63, wave = tid >> 6;
  int half = lane >> 5, off = lane & 31;
  float e1 = 1.0f + epsp[0];

  // ---- agg phase ----
#pragma unroll
  for (int which = 0; which < 2; ++which) {
    int row = wave * 2 + which;
    int node = m0 + row;
    float a[8];
    if (node < NN) {
      us8 sv = xb8[node * 32 + off];
      float selfw = half ? 0.0f : e1;
#pragma unroll
      for (int j = 0; j < 8; ++j) a[j] = bf2f(sv[j]) * selfw;
      int n = min(cnt[node], CAP);
      const int4* bp4 = reinterpret_cast<const int4*>(bucket + node * CAP);
      int4 ia = bp4[0], ib = bp4[1];
      int k = 0;
      while (k + 8 <= n) {
        int4 na = bp4[(k >> 2) + 2];  // prefetch (pad covers overreach)
        int4 nb = bp4[(k >> 2) + 3];
        int r0 = half ? ia.y : ia.x;
        int r1 = half ? ia.w : ia.z;
        int r2 = half ? ib.y : ib.x;
        int r3 = half ? ib.w : ib.z;
        us8 v0 = xb8[r0 * 32 + off];
        us8 v1 = xb8[r1 * 32 + off];
        us8 v2 = xb8[r2 * 32 + off];
        us8 v3 = xb8[r3 * 32 + off];
#pragma unroll
        for (int j = 0; j < 8; ++j)
          a[j] += (bf2f(v0[j]) + bf2f(v1[j])) + (bf2f(v2[j]) + bf2f(v3[j]));
        ia = na; ib = nb; k += 8;
      }
      int tl = n - k;  // 0..7, indices live in ia/ib
#pragma unroll
      for (int q = 0; q < 4; ++q) {
        int idx = (q == 0) ? (half ? ia.y : ia.x)
                : (q == 1) ? (half ? ia.w : ia.z)
                : (q == 2) ? (half ? ib.y : ib.x)
                           : (half ? ib.w : ib.z);
        if (2 * q + half < tl) {
          us8 v = xb8[idx * 32 + off];
#pragma unroll
          for (int j = 0; j < 8; ++j) a[j] += bf2f(v[j]);
        }
      }
#pragma unroll
      for (int j = 0; j < 8; ++j) a[j] += __shfl_xor(a[j], 32);
    } else {
#pragma unroll
      for (int j = 0; j < 8; ++j) a[j] = 0.0f;
    }
    if (half == 0) {
      us8 o;
#pragma unroll
      for (int j = 0; j < 8; ++j) o[j] = f2bf(a[j]);
      *reinterpret_cast<us8*>(&As[row][off * 8]) = o;
    }
  }

  // ---- MLP phase: 2M x 8N waves ----
  int waveM = wave & 1, waveN = wave >> 1;  // waveN 0..7
  int l15 = lane & 15, g = lane >> 4;
  float bias1[2], bias2[2];
#pragma unroll
  for (int ni = 0; ni < 2; ++ni) {
    int col = waveN * 32 + ni * 16 + l15;
    bias1[ni] = b1[col];
    bias2[ni] = b2[col];
  }

  // prologue: stage W1 chunk 0 (reg -> LDS)
  int4 rv[2];
#pragma unroll
  for (int i = 0; i < 2; ++i) {
    int c = tid + i * 1024;
    int n = c >> 3, kc = c & 7;
    rv[i] = *reinterpret_cast<const int4*>(&w1t[n * 256 + kc * 8]);
  }
#pragma unroll
  for (int i = 0; i < 2; ++i) {
    int c = tid + i * 1024;
    int n = c >> 3, kc = c & 7;
    *reinterpret_cast<int4*>(&Bs[n][kc * 8]) = rv[i];
  }
  __syncthreads();  // orders agg As writes + Bs chunk0 before MFMA reads

  f32x4 acc[2];
  acc[0] = f32x4{0.f, 0.f, 0.f, 0.f};
  acc[1] = f32x4{0.f, 0.f, 0.f, 0.f};

#pragma unroll
  for (int cc2 = 0; cc2 < 8; ++cc2) {  // chunks 0-3: W1, 4-7: W2
    int k0 = (cc2 & 3) * 64;
    if (cc2 < 7) {  // issue next chunk's global loads EARLY (hide under MFMA)
      const unsigned short* wt = (cc2 + 1 < 4) ? w1t : w2t;
      int kn = ((cc2 + 1) & 3) * 64;
#pragma unroll
      for (int i = 0; i < 2; ++i) {
        int c = tid + i * 1024;
        int n = c >> 3, kc = c & 7;
        rv[i] = *reinterpret_cast<const int4*>(&wt[n * 256 + kn + kc * 8]);
      }
    }
#pragma unroll
    for (int kk = 0; kk < 2; ++kk) {
      bf16x8 af = *reinterpret_cast<const bf16x8*>(
          &As[waveM * 16 + l15][k0 + kk * 32 + g * 8]);
#pragma unroll
      for (int ni = 0; ni < 2; ++ni) {
        bf16x8 bfr = *reinterpret_cast<const bf16x8*>(
            &Bs[waveN * 32 + ni * 16 + l15][kk * 32 + g * 8]);
        acc[ni] = __builtin_amdgcn_mfma_f32_16x16x32_bf16(af, bfr, acc[ni], 0, 0, 0);
      }
    }
    if (cc2 < 7) {
      __syncthreads();  // all waves done reading Bs (and As for cc2==3)
      if (cc2 == 3) {   // relu(acc + b1) -> As; reset acc for GEMM2
#pragma unroll
        for (int ni = 0; ni < 2; ++ni) {
          int col = waveN * 32 + ni * 16 + l15;
#pragma unroll
          for (int r = 0; r < 4; ++r) {
            int row = waveM * 16 + g * 4 + r;
            As[row][col] = f2bf(fmaxf(acc[ni][r] + bias1[ni], 0.f));
          }
          acc[ni] = f32x4{0.f, 0.f, 0.f, 0.f};
        }
      }
#pragma unroll
      for (int i = 0; i < 2; ++i) {  // reg -> LDS for next chunk
        int c = tid + i * 1024;
        int n = c >> 3, kc = c & 7;
        *reinterpret_cast<int4*>(&Bs[n][kc * 8]) = rv[i];
      }
      __syncthreads();
    }
  }

  // epilogue: out = acc + b2 (f32)
#pragma unroll
  for (int ni = 0; ni < 2; ++ni) {
    int col = waveN * 32 + ni * 16 + l15;
#pragma unroll
    for (int r = 0; r < 4; ++r) {
      int row = m0 + waveM * 16 + g * 4 + r;
      if (row < NN) out[row * 256 + col] = acc[ni][r] + bias2[ni];
    }
  }
}

// ---- launch ---------------------------------------------------------------

extern "C" void kernel_launch(void* const* d_in, const int* in_sizes, int n_in,
                              void* d_out, int out_size, void* d_ws, size_t ws_size,
                              hipStream_t stream) {
  const float* x = (const float*)d_in[0];
  const int* ei = (const int*)d_in[1];
  const float* w1 = (const float*)d_in[2];
  const float* b1 = (const float*)d_in[3];
  const float* w2 = (const float*)d_in[4];
  const float* b2 = (const float*)d_in[5];
  const float* eps = (const float*)d_in[6];
  float* out = (float*)d_out;

  // workspace layout (16B aligned throughout)
  int* cnt = (int*)d_ws;                              // 10240 ints
  int* bucket = cnt + 10240;                          // NN*CAP ints + 32 pad
  unsigned short* xb = (unsigned short*)(bucket + NN * CAP + 32);  // NN*256 bf16
  unsigned short* w1t = xb + NN * 256;                // 65536 bf16
  unsigned short* w2t = w1t + 65536;                  // 65536 bf16

  conv_k<<<2532, 256, 0, stream>>>(x, w1, w2, (ushort4*)xb, w1t, w2t, cnt);
  fill_k<<<(NE / 4 + 255) / 256, 256, 0, stream>>>(ei, cnt, bucket);
  fused_k<<<(NN + 31) / 32, 1024, 0, stream>>>((const us8*)xb, cnt, bucket, eps,
                                               w1t, b1, w2t, b2, out);
}

// Round 12
// 60.424 us; speedup vs baseline: 1.4636x; 1.4636x over previous
//
#include <hip/hip_runtime.h>

#define NN 10000
#define NE 320000
#define RCAP 64   /* per-replica segment capacity */
#define BSTRIDE 128

typedef __bf16 bf16x8 __attribute__((ext_vector_type(8)));
typedef float f32x4 __attribute__((ext_vector_type(4)));
typedef unsigned short us8 __attribute__((ext_vector_type(8)));

static __device__ __forceinline__ unsigned short f2bf(float f) {
  union { float fv; unsigned u; } v; v.fv = f;
  unsigned r = v.u + 0x7FFFu + ((v.u >> 16) & 1u);
  return (unsigned short)(r >> 16);
}
static __device__ __forceinline__ float bf2f(unsigned short b) {
  union { unsigned u; float f; } v; v.u = ((unsigned)b) << 16;
  return v.f;
}

// ---- D1: x->bf16 (blocks 0..2499) + cnt zero (both replicas) + weight
//      transpose (blocks 2500..2531). r8-validated structure. --------------

__global__ __launch_bounds__(256) void conv_k(const float* __restrict__ x,
                                              const float* __restrict__ w1,
                                              const float* __restrict__ w2,
                                              ushort4* __restrict__ xb4,
                                              unsigned short* __restrict__ w1t,
                                              unsigned short* __restrict__ w2t,
                                              int* __restrict__ cnt) {
  __shared__ unsigned short sh[64][72];
  int bid = blockIdx.x, tid = threadIdx.x;
  if (bid < 2500) {
    int t = bid * 256 + tid;
    if (t < 20480) cnt[t] = 0;  // both replica arrays
    float4 v = reinterpret_cast<const float4*>(x)[t];
    ushort4 o;
    o.x = f2bf(v.x); o.y = f2bf(v.y); o.z = f2bf(v.z); o.w = f2bf(v.w);
    xb4[t] = o;
  } else {
    int b2 = bid - 2500;                       // 0..31
    const float* w = (b2 & 16) ? w2 : w1;
    unsigned short* wt = (b2 & 16) ? w2t : w1t;
    int tile = b2 & 15;
    int ki0 = (tile >> 2) * 64, ni0 = (tile & 3) * 64;
    int r = tid >> 4, c = tid & 15;
#pragma unroll
    for (int rr = r; rr < 64; rr += 16) {
      float4 v = *reinterpret_cast<const float4*>(&w[(ki0 + rr) * 256 + ni0 + c * 4]);
      ushort4 o;
      o.x = f2bf(v.x); o.y = f2bf(v.y); o.z = f2bf(v.z); o.w = f2bf(v.w);
      *reinterpret_cast<ushort4*>(&sh[rr][c * 4]) = o;
    }
    __syncthreads();
    int n = tid >> 3, c8 = tid & 7;
#pragma unroll
    for (int nn = n; nn < 64; nn += 32) {
      us8 o;
#pragma unroll
      for (int j = 0; j < 8; ++j) o[j] = sh[c8 * 8 + j][nn];
      *reinterpret_cast<us8*>(&wt[(ni0 + nn) * 256 + ki0 + c8 * 8]) = o;
    }
  }
}

// ---- D2: bucket fill, 2-way replicated counters (edge j -> replica j&1) ---

__global__ __launch_bounds__(256) void fill_k(const int* __restrict__ ei,
                                              int* __restrict__ cnt,
                                              int* __restrict__ bucket) {
  int e = (blockIdx.x * 256 + threadIdx.x) * 4;
  if (e < NE) {
    int4 s = *reinterpret_cast<const int4*>(&ei[e]);
    int4 d = *reinterpret_cast<const int4*>(&ei[NE + e]);
    int p;
    // edges e+0,e+2 -> replica 0 ; e+1,e+3 -> replica 1
    p = atomicAdd(&cnt[d.x], 1);
    if (p < RCAP) bucket[d.x * BSTRIDE + p] = s.x;
    p = atomicAdd(&cnt[10240 + d.y], 1);
    if (p < RCAP) bucket[d.y * BSTRIDE + RCAP + p] = s.y;
    p = atomicAdd(&cnt[d.z], 1);
    if (p < RCAP) bucket[d.z * BSTRIDE + p] = s.z;
    p = atomicAdd(&cnt[10240 + d.w], 1);
    if (p < RCAP) bucket[d.w * BSTRIDE + RCAP + p] = s.w;
  }
}

// ---- D3: aggregation v2r: 2 waves/node, wave p owns replica-p segment. ----
// Same r8-validated deep pipeline (8 gathers in flight via us8 2-row loads),
// shfl_xor(32) + LDS combine. Segment split replaces the old range split.

__global__ __launch_bounds__(256) void agg_k(const us8* __restrict__ xb8,
                                             const int* __restrict__ cnt,
                                             const int* __restrict__ bucket,
                                             const float* __restrict__ epsp,
                                             unsigned short* __restrict__ hb) {
  __shared__ float part[2][256];
  int tid = threadIdx.x;
  int wave = tid >> 6;
  int slot = wave >> 1;   // which node of the block's pair
  int p = wave & 1;       // which replica segment
  int node = blockIdx.x * 2 + slot;   // grid = NN/2 exactly
  int lane = tid & 63;
  int half = lane >> 5, off = lane & 31;
  float e1 = 1.0f + epsp[0];

  float a[8];
  if (p == 0) {
    us8 sv = xb8[node * 32 + off];
    float selfw = half ? 0.0f : e1;
#pragma unroll
    for (int j = 0; j < 8; ++j) a[j] = bf2f(sv[j]) * selfw;
  } else {
#pragma unroll
    for (int j = 0; j < 8; ++j) a[j] = 0.0f;
  }

  int m = min(cnt[p * 10240 + node], RCAP);
  const int4* bp4 = reinterpret_cast<const int4*>(bucket + node * BSTRIDE + p * RCAP);
  int4 ia = bp4[0], ib = bp4[1];
  int k = 0;
  while (k + 8 <= m) {
    int4 na = bp4[(k >> 2) + 2];  // prefetch next 8 indices (pad-safe)
    int4 nb = bp4[(k >> 2) + 3];
    int r0 = half ? ia.y : ia.x;
    int r1 = half ? ia.w : ia.z;
    int r2 = half ? ib.y : ib.x;
    int r3 = half ? ib.w : ib.z;
    us8 v0 = xb8[r0 * 32 + off];
    us8 v1 = xb8[r1 * 32 + off];
    us8 v2 = xb8[r2 * 32 + off];
    us8 v3 = xb8[r3 * 32 + off];
#pragma unroll
    for (int j = 0; j < 8; ++j)
      a[j] += (bf2f(v0[j]) + bf2f(v1[j])) + (bf2f(v2[j]) + bf2f(v3[j]));
    ia = na; ib = nb; k += 8;
  }
  int tl = m - k;  // 0..7 remaining, indices live in ia/ib
#pragma unroll
  for (int q = 0; q < 4; ++q) {
    int idx = (q == 0) ? (half ? ia.y : ia.x)
            : (q == 1) ? (half ? ia.w : ia.z)
            : (q == 2) ? (half ? ib.y : ib.x)
                       : (half ? ib.w : ib.z);
    if (2 * q + half < tl) {  // garbage idx never dereferenced
      us8 v = xb8[idx * 32 + off];
#pragma unroll
      for (int j = 0; j < 8; ++j) a[j] += bf2f(v[j]);
    }
  }
#pragma unroll
  for (int j = 0; j < 8; ++j) a[j] += __shfl_xor(a[j], 32);  // combine halves
  if (p == 1 && half == 0) {
#pragma unroll
    for (int j = 0; j < 8; ++j) part[slot][j * 32 + off] = a[j];
  }
  __syncthreads();
  if (p == 0 && half == 0) {
    us8 o;
#pragma unroll
    for (int j = 0; j < 8; ++j) o[j] = f2bf(a[j] + part[slot][j * 32 + off]);
    *reinterpret_cast<us8*>(&hb[node * 256 + off * 8]) = o;
  }
}

// ---- D4: fused MLP: out = (relu(hb@W1+b1))@W2 + b2 (r3/r8-validated) ------

__global__ __launch_bounds__(256) void mlp_k(const unsigned short* __restrict__ hb,
                                             const unsigned short* __restrict__ w1t,
                                             const float* __restrict__ b1,
                                             const unsigned short* __restrict__ w2t,
                                             const float* __restrict__ b2,
                                             float* __restrict__ out) {
  __shared__ unsigned short As[32][264];
  __shared__ unsigned short Bs[256][72];
  int m0 = blockIdx.x * 32;
  int tid = threadIdx.x;
  int lane = tid & 63, wave = tid >> 6;
  int waveM = wave & 1, waveN = wave >> 1;
  int l15 = lane & 15, g = lane >> 4;
#pragma unroll
  for (int i = 0; i < 4; ++i) {
    int c = tid + i * 256;
    int r = c >> 5, cc = c & 31;
    int4 v = (m0 + r < NN)
                 ? *reinterpret_cast<const int4*>(&hb[(m0 + r) * 256 + cc * 8])
                 : make_int4(0, 0, 0, 0);
    *reinterpret_cast<int4*>(&As[r][cc * 8]) = v;
  }
  float bias1[8], bias2[8];
#pragma unroll
  for (int ni = 0; ni < 8; ++ni) {
    int col = waveN * 128 + ni * 16 + l15;
    bias1[ni] = b1[col];
    bias2[ni] = b2[col];
  }
  f32x4 acc[8];
#pragma unroll
  for (int ni = 0; ni < 8; ++ni) acc[ni] = f32x4{0.f, 0.f, 0.f, 0.f};
  for (int k0 = 0; k0 < 256; k0 += 64) {
#pragma unroll
    for (int i = 0; i < 8; ++i) {
      int c = tid + i * 256;
      int n = c >> 3, kc = c & 7;
      *reinterpret_cast<int4*>(&Bs[n][kc * 8]) =
          *reinterpret_cast<const int4*>(&w1t[n * 256 + k0 + kc * 8]);
    }
    __syncthreads();
#pragma unroll
    for (int kk = 0; kk < 2; ++kk) {
      bf16x8 af = *reinterpret_cast<const bf16x8*>(
          &As[waveM * 16 + l15][k0 + kk * 32 + g * 8]);
#pragma unroll
      for (int ni = 0; ni < 8; ++ni) {
        bf16x8 bfr = *reinterpret_cast<const bf16x8*>(
            &Bs[waveN * 128 + ni * 16 + l15][kk * 32 + g * 8]);
        acc[ni] = __builtin_amdgcn_mfma_f32_16x16x32_bf16(af, bfr, acc[ni], 0, 0, 0);
      }
    }
    __syncthreads();
  }
#pragma unroll
  for (int ni = 0; ni < 8; ++ni) {
    int col = waveN * 128 + ni * 16 + l15;
#pragma unroll
    for (int r = 0; r < 4; ++r) {
      int row = waveM * 16 + g * 4 + r;
      As[row][col] = f2bf(fmaxf(acc[ni][r] + bias1[ni], 0.f));
    }
    acc[ni] = f32x4{0.f, 0.f, 0.f, 0.f};
  }
  for (int k0 = 0; k0 < 256; k0 += 64) {
#pragma unroll
    for (int i = 0; i < 8; ++i) {
      int c = tid + i * 256;
      int n = c >> 3, kc = c & 7;
      *reinterpret_cast<int4*>(&Bs[n][kc * 8]) =
          *reinterpret_cast<const int4*>(&w2t[n * 256 + k0 + kc * 8]);
    }
    __syncthreads();
#pragma unroll
    for (int kk = 0; kk < 2; ++kk) {
      bf16x8 af = *reinterpret_cast<const bf16x8*>(
          &As[waveM * 16 + l15][k0 + kk * 32 + g * 8]);
#pragma unroll
      for (int ni = 0; ni < 8; ++ni) {
        bf16x8 bfr = *reinterpret_cast<const bf16x8*>(
            &Bs[waveN * 128 + ni * 16 + l15][kk * 32 + g * 8]);
        acc[ni] = __builtin_amdgcn_mfma_f32_16x16x32_bf16(af, bfr, acc[ni], 0, 0, 0);
      }
    }
    __syncthreads();
  }
#pragma unroll
  for (int ni = 0; ni < 8; ++ni) {
    int col = waveN * 128 + ni * 16 + l15;
#pragma unroll
    for (int r = 0; r < 4; ++r) {
      int row = m0 + waveM * 16 + g * 4 + r;
      if (row < NN) out[row * 256 + col] = acc[ni][r] + bias2[ni];
    }
  }
}

// ---- launch ---------------------------------------------------------------

extern "C" void kernel_launch(void* const* d_in, const int* in_sizes, int n_in,
                              void* d_out, int out_size, void* d_ws, size_t ws_size,
                              hipStream_t stream) {
  const float* x = (const float*)d_in[0];
  const int* ei = (const int*)d_in[1];
  const float* w1 = (const float*)d_in[2];
  const float* b1 = (const float*)d_in[3];
  const float* w2 = (const float*)d_in[4];
  const float* b2 = (const float*)d_in[5];
  const float* eps = (const float*)d_in[6];
  float* out = (float*)d_out;

  // workspace layout (16B aligned throughout)
  int* cnt = (int*)d_ws;                              // 2 x 10240 ints
  int* bucket = cnt + 20480;                          // NN*BSTRIDE + 32 pad ints
  unsigned short* xb = (unsigned short*)(bucket + NN * BSTRIDE + 32);
  unsigned short* w1t = xb + NN * 256;                // 65536 bf16
  unsigned short* w2t = w1t + 65536;                  // 65536 bf16
  unsigned short* hb = w2t + 65536;                   // NN*256 bf16

  conv_k<<<2532, 256, 0, stream>>>(x, w1, w2, (ushort4*)xb, w1t, w2t, cnt);
  fill_k<<<(NE / 4 + 255) / 256, 256, 0, stream>>>(ei, cnt, bucket);
  agg_k<<<NN / 2, 256, 0, stream>>>((const us8*)xb, cnt, bucket, eps, hb);
  mlp_k<<<(NN + 31) / 32, 256, 0, stream>>>(hb, w1t, b1, w2t, b2, out);
}